// Round 1
// baseline (424.258 us; speedup 1.0000x reference)
//
#include <hip/hip_runtime.h>

// MRMSNorm: x (4,4096,4096) fp32, scale (4096,) fp32.
// Per row: 5 nested RMS norms at prefix sizes {256,512,1024,2048,4096}.
// out[d] = x[d] * rsqrt(sumsq(x[0:s])/s + 1e-6) * scale[d], s = segment of d.
//
// One block per row (16384 blocks, 256 threads). Row lives in registers
// (4x float4 per thread). Single read of x, single write of out -> 512 MB
// total HBM traffic, memory-bound at ~81 us floor.

#define D 4096

__global__ __launch_bounds__(256) void mrms_kernel(
    const float* __restrict__ x,
    const float* __restrict__ scale,
    float* __restrict__ out)
{
    const int row = blockIdx.x;
    const size_t base = (size_t)row * D;
    const float4* __restrict__ xr   = reinterpret_cast<const float4*>(x + base);
    float4* __restrict__ outr       = reinterpret_cast<float4*>(out + base);
    const float4* __restrict__ sc4  = reinterpret_cast<const float4*>(scale);

    const int t = threadIdx.x;

    // Coalesced load of the whole row: thread t takes float4 at positions
    // t, t+256, t+512, t+768  -> cols [4t..4t+3] in chunks of 1024 floats.
    float4 v0 = xr[t];
    float4 v1 = xr[t + 256];
    float4 v2 = xr[t + 512];
    float4 v3 = xr[t + 768];

    float p0 = v0.x*v0.x + v0.y*v0.y + v0.z*v0.z + v0.w*v0.w;
    float p1 = v1.x*v1.x + v1.y*v1.y + v1.z*v1.z + v1.w*v1.w;
    float p2 = v2.x*v2.x + v2.y*v2.y + v2.z*v2.z + v2.w*v2.w;
    float p3 = v3.x*v3.x + v3.y*v3.y + v3.z*v3.z + v3.w*v3.w;

    // Segment membership (segments at col {0,256,512,1024,2048,4096}):
    // chunk0 (cols [0,1024)):  t<64 -> seg0 [0,256); t<128 -> seg1 [256,512);
    //                          else -> seg2 [512,1024)
    // chunk1 (cols [1024,2048)) -> seg3 ; chunks2+3 (cols [2048,4096)) -> seg4
    float s0 = (t < 64)              ? p0 : 0.0f;
    float s1 = (t >= 64 && t < 128)  ? p0 : 0.0f;
    float s2 = (t >= 128)            ? p0 : 0.0f;
    float s3 = p1;
    float s4 = p2 + p3;

    // Deterministic 64-lane wave reduction for each of the 5 segment sums.
    #pragma unroll
    for (int off = 32; off > 0; off >>= 1) {
        s0 += __shfl_down(s0, off, 64);
        s1 += __shfl_down(s1, off, 64);
        s2 += __shfl_down(s2, off, 64);
        s3 += __shfl_down(s3, off, 64);
        s4 += __shfl_down(s4, off, 64);
    }

    __shared__ float lds[4][5];
    const int wave = t >> 6;
    if ((t & 63) == 0) {
        lds[wave][0] = s0;
        lds[wave][1] = s1;
        lds[wave][2] = s2;
        lds[wave][3] = s3;
        lds[wave][4] = s4;
    }
    __syncthreads();

    // Every thread rebuilds the 5 cumulative sums (broadcast LDS reads).
    float c0 = lds[0][0] + lds[1][0] + lds[2][0] + lds[3][0];
    float c1 = lds[0][1] + lds[1][1] + lds[2][1] + lds[3][1];
    float c2 = lds[0][2] + lds[1][2] + lds[2][2] + lds[3][2];
    float c3 = lds[0][3] + lds[1][3] + lds[2][3] + lds[3][3];
    float c4 = lds[0][4] + lds[1][4] + lds[2][4] + lds[3][4];

    const float cum0 = c0;
    const float cum1 = cum0 + c1;
    const float cum2 = cum1 + c2;
    const float cum3 = cum2 + c3;
    const float cum4 = cum3 + c4;

    const float EPS = 1e-6f;
    const float r0 = rsqrtf(cum0 * (1.0f / 256.0f)  + EPS);
    const float r1 = rsqrtf(cum1 * (1.0f / 512.0f)  + EPS);
    const float r2 = rsqrtf(cum2 * (1.0f / 1024.0f) + EPS);
    const float r3 = rsqrtf(cum3 * (1.0f / 2048.0f) + EPS);
    const float r4 = rsqrtf(cum4 * (1.0f / 4096.0f) + EPS);

    // rrms for this thread's chunk-0 float4 (whole float4 is in one segment).
    const float rc0 = (t < 64) ? r0 : ((t < 128) ? r1 : r2);

    // scale is tiny (16 KB) -> L2/L1 resident broadcast across blocks.
    float4 g0 = sc4[t];
    float4 g1 = sc4[t + 256];
    float4 g2 = sc4[t + 512];
    float4 g3 = sc4[t + 768];

    float4 o;
    o.x = v0.x * rc0 * g0.x;  o.y = v0.y * rc0 * g0.y;
    o.z = v0.z * rc0 * g0.z;  o.w = v0.w * rc0 * g0.w;
    outr[t] = o;

    o.x = v1.x * r3 * g1.x;   o.y = v1.y * r3 * g1.y;
    o.z = v1.z * r3 * g1.z;   o.w = v1.w * r3 * g1.w;
    outr[t + 256] = o;

    o.x = v2.x * r4 * g2.x;   o.y = v2.y * r4 * g2.y;
    o.z = v2.z * r4 * g2.z;   o.w = v2.w * r4 * g2.w;
    outr[t + 512] = o;

    o.x = v3.x * r4 * g3.x;   o.y = v3.y * r4 * g3.y;
    o.z = v3.z * r4 * g3.z;   o.w = v3.w * r4 * g3.w;
    outr[t + 768] = o;
}

extern "C" void kernel_launch(void* const* d_in, const int* in_sizes, int n_in,
                              void* d_out, int out_size, void* d_ws, size_t ws_size,
                              hipStream_t stream) {
    const float* x     = (const float*)d_in[0];
    const float* scale = (const float*)d_in[1];
    float* out         = (float*)d_out;

    const int nrows = in_sizes[0] / D;  // 4 * 4096 = 16384
    mrms_kernel<<<nrows, 256, 0, stream>>>(x, scale, out);
}

// Round 4
// 414.371 us; speedup vs baseline: 1.0239x; 1.0239x over previous
//
#include <hip/hip_runtime.h>

// MRMSNorm: x (4,4096,4096) fp32, scale (4096,) fp32.
// Per row: 5 nested RMS norms at prefix sizes {256,512,1024,2048,4096}.
// out[d] = x[d] * rsqrt(sumsq(x[0:s])/s + 1e-6) * scale[d], s = segment of d.
//
// One block per row (16384 blocks, 256 threads). Row lives in registers
// (4x float4 per thread). Single read of x, single write of out.
//
// Wave-aligned segments: thread t's chunk-0 float4 covers cols [4t,4t+4), so
//   wave0 (t 0..63)    -> cols [0,256)    = seg0
//   wave1 (t 64..127)  -> cols [256,512)  = seg1
//   waves2-3           -> cols [512,1024) = seg2
// => no per-lane masking; each wave reduces only {p0, p1, p2+p3} (3 chains,
// not 5), and segment assignment happens at the 4x3 LDS combine.
//
// NOTE: __builtin_nontemporal_* requires a NATIVE clang vector type —
// HIP's float4 (HIP_vector_type class) is rejected. Use ext_vector_type.

#define D 4096

typedef float f32x4 __attribute__((ext_vector_type(4)));

__global__ __launch_bounds__(256) void mrms_kernel(
    const float* __restrict__ x,
    const float* __restrict__ scale,
    float* __restrict__ out)
{
    const int row = blockIdx.x;
    const size_t base = (size_t)row * D;
    const f32x4* __restrict__ xr  = reinterpret_cast<const f32x4*>(x + base);
    f32x4* __restrict__ outr      = reinterpret_cast<f32x4*>(out + base);
    const f32x4* __restrict__ sc4 = reinterpret_cast<const f32x4*>(scale);

    const int t = threadIdx.x;

    // Issue all vmem loads up front; x/out are stream-once -> non-temporal.
    f32x4 v0 = __builtin_nontemporal_load(&xr[t]);
    f32x4 v1 = __builtin_nontemporal_load(&xr[t + 256]);
    f32x4 v2 = __builtin_nontemporal_load(&xr[t + 512]);
    f32x4 v3 = __builtin_nontemporal_load(&xr[t + 768]);
    f32x4 g0 = sc4[t];
    f32x4 g1 = sc4[t + 256];
    f32x4 g2 = sc4[t + 512];
    f32x4 g3 = sc4[t + 768];

    float a = v0.x*v0.x + v0.y*v0.y + v0.z*v0.z + v0.w*v0.w;   // own chunk0
    float b = v1.x*v1.x + v1.y*v1.y + v1.z*v1.z + v1.w*v1.w;   // seg3 part
    float c = v2.x*v2.x + v2.y*v2.y + v2.z*v2.z + v2.w*v2.w
            + v3.x*v3.x + v3.y*v3.y + v3.z*v3.z + v3.w*v3.w;   // seg4 part

    // 3 deterministic 64-lane reduction chains (18 shuffles total).
    #pragma unroll
    for (int off = 32; off > 0; off >>= 1) {
        a += __shfl_down(a, off, 64);
        b += __shfl_down(b, off, 64);
        c += __shfl_down(c, off, 64);
    }

    __shared__ float lds[4][3];
    const int wave = t >> 6;
    if ((t & 63) == 0) {
        lds[wave][0] = a;
        lds[wave][1] = b;
        lds[wave][2] = c;
    }
    __syncthreads();

    // Segment sums from the 4x3 table (broadcast reads, conflict-free).
    const float seg0 = lds[0][0];                                // [0,256)
    const float seg1 = lds[1][0];                                // [256,512)
    const float seg2 = lds[2][0] + lds[3][0];                    // [512,1024)
    const float seg3 = lds[0][1] + lds[1][1] + lds[2][1] + lds[3][1]; // [1024,2048)
    const float seg4 = lds[0][2] + lds[1][2] + lds[2][2] + lds[3][2]; // [2048,4096)

    const float cum0 = seg0;
    const float cum1 = cum0 + seg1;
    const float cum2 = cum1 + seg2;
    const float cum3 = cum2 + seg3;
    const float cum4 = cum3 + seg4;

    const float EPS = 1e-6f;
    const float r0 = rsqrtf(cum0 * (1.0f / 256.0f)  + EPS);
    const float r1 = rsqrtf(cum1 * (1.0f / 512.0f)  + EPS);
    const float r2 = rsqrtf(cum2 * (1.0f / 1024.0f) + EPS);
    const float r3 = rsqrtf(cum3 * (1.0f / 2048.0f) + EPS);
    const float r4 = rsqrtf(cum4 * (1.0f / 4096.0f) + EPS);

    // rrms for this thread's chunk-0 float4 (whole float4 in one segment,
    // and per-wave uniform -> no divergence cost).
    const float rc0 = (t < 64) ? r0 : ((t < 128) ? r1 : r2);

    f32x4 o;
    o.x = v0.x * rc0 * g0.x;  o.y = v0.y * rc0 * g0.y;
    o.z = v0.z * rc0 * g0.z;  o.w = v0.w * rc0 * g0.w;
    __builtin_nontemporal_store(o, &outr[t]);

    o.x = v1.x * r3 * g1.x;   o.y = v1.y * r3 * g1.y;
    o.z = v1.z * r3 * g1.z;   o.w = v1.w * r3 * g1.w;
    __builtin_nontemporal_store(o, &outr[t + 256]);

    o.x = v2.x * r4 * g2.x;   o.y = v2.y * r4 * g2.y;
    o.z = v2.z * r4 * g2.z;   o.w = v2.w * r4 * g2.w;
    __builtin_nontemporal_store(o, &outr[t + 512]);

    o.x = v3.x * r4 * g3.x;   o.y = v3.y * r4 * g3.y;
    o.z = v3.z * r4 * g3.z;   o.w = v3.w * r4 * g3.w;
    __builtin_nontemporal_store(o, &outr[t + 768]);
}

extern "C" void kernel_launch(void* const* d_in, const int* in_sizes, int n_in,
                              void* d_out, int out_size, void* d_ws, size_t ws_size,
                              hipStream_t stream) {
    const float* x     = (const float*)d_in[0];
    const float* scale = (const float*)d_in[1];
    float* out         = (float*)d_out;

    const int nrows = in_sizes[0] / D;  // 4 * 4096 = 16384
    mrms_kernel<<<nrows, 256, 0, stream>>>(x, scale, out);
}